// Round 1
// baseline (146.401 us; speedup 1.0000x reference)
//
#include <hip/hip_runtime.h>
#include <hip/hip_bf16.h>
#include <cstddef>
#include <cstdint>

#define B_ 8
#define H_ 8
#define N_ 512
#define K_ 16
#define NN_ (N_*N_)

static constexpr float ALPHA_C = 0.001f;

// -------------------------------------------------------------------------
// Kernel 1: per (b,n): A = sum_g phi[g]*G_g (skew), Om = expm(A) via
// scaling-and-squaring + Taylor-8 Horner, v = Om^T mu, q = 0.5*||v||^2.
// One 256-thread block per matrix; thread (r,c) owns element [r][c].
// -------------------------------------------------------------------------
__global__ __launch_bounds__(256) void expm_kernel(
    const float* __restrict__ mu, const float* __restrict__ phi,
    const float* __restrict__ gen, float* __restrict__ Om,
    float* __restrict__ v, float* __restrict__ q)
{
    const int bn  = blockIdx.x;          // 0..B_*N_-1
    const int tid = threadIdx.x;         // 0..255
    const int r = tid >> 4, c = tid & 15;
    const int rc = (r << 4) | c;
    const int r17 = r * 17;

    __shared__ float Xs[16*17];
    __shared__ float Ps[16*17];
    __shared__ float red[256];
    __shared__ float mus[16];
    __shared__ float vs[16];

    const float p0 = phi[bn*3+0], p1 = phi[bn*3+1], p2 = phi[bn*3+2];
    float A = p0*gen[rc] + p1*gen[256+rc] + p2*gen[512+rc];

    // Frobenius norm (upper bound on spectral norm) -> scaling exponent s
    red[tid] = A * A;
    __syncthreads();
    for (int st = 128; st > 0; st >>= 1) {
        if (tid < st) red[tid] += red[tid + st];
        __syncthreads();
    }
    float theta = sqrtf(red[0]);
    int s = 0;
    while (theta > 0.25f && s < 24) { theta *= 0.5f; s++; }
    const float X = A * exp2f((float)(-s));

    if (tid < 16) mus[tid] = mu[bn*16 + tid];

    // Horner for Taylor-8: P = I + X(I + X/2(I + ... (I + X/8)...))
    Xs[r17 + c] = X;
    Ps[r17 + c] = ((r == c) ? 1.0f : 0.0f) + X * 0.125f;
    __syncthreads();

    for (int d = 7; d >= 1; --d) {
        float t = 0.f;
        #pragma unroll
        for (int k = 0; k < 16; ++k) t = fmaf(Xs[r17 + k], Ps[k*17 + c], t);
        __syncthreads();
        Ps[r17 + c] = ((r == c) ? 1.0f : 0.0f) + t * (1.0f / (float)d);
        __syncthreads();
    }
    // square s times
    for (int it = 0; it < s; ++it) {
        float t = 0.f;
        #pragma unroll
        for (int k = 0; k < 16; ++k) t = fmaf(Ps[r17 + k], Ps[k*17 + c], t);
        __syncthreads();
        Ps[r17 + c] = t;
        __syncthreads();
    }

    // store Om (row-major, coalesced)
    Om[(size_t)bn * 256 + rc] = Ps[r17 + c];

    // v[k] = sum_m Om[m][k] * mu[m]   (Om^T mu)
    if (tid < 16) {
        float acc = 0.f;
        #pragma unroll
        for (int m = 0; m < 16; ++m) acc = fmaf(Ps[m*17 + tid], mus[m], acc);
        vs[tid] = acc;
        v[bn*16 + tid] = acc;
    }
    __syncthreads();
    if (tid == 0) {
        float acc = 0.f;
        #pragma unroll
        for (int k = 0; k < 16; ++k) acc = fmaf(vs[k], vs[k], acc);
        q[bn] = 0.5f * acc;
    }
}

// -------------------------------------------------------------------------
// Kernel 2: memory-bound pass over beta. One wave per (b,i); 4 i per block
// sharing a transposed LDS copy of v[b] (row stride 513 -> conflict-free).
// Per lane: j = lane + 64p, p=0..7. Accumulate w1, w2, s, R; butterfly
// reduce; rotate by Om_i; write mu update.
// -------------------------------------------------------------------------
__global__ __launch_bounds__(256, 4) void grad_kernel(
    const float* __restrict__ mu, const float* __restrict__ beta,
    const float* __restrict__ mu_prior, const float* __restrict__ lrp,
    const float* __restrict__ Om, const float* __restrict__ v,
    const float* __restrict__ q, float* __restrict__ out)
{
    __shared__ float v_t[16 * 513];
    __shared__ float q_lds[512];

    const int blk = blockIdx.x;          // 0..1023
    const int b   = blk >> 7;            // / (N_/4)
    const int i0  = (blk & 127) << 2;
    const int tid = threadIdx.x;
    const int wid = tid >> 6, lane = tid & 63;

    // stage v[b] transposed into LDS (coalesced global read)
    const float* vb = v + (size_t)b * N_ * K_;
    for (int f = tid; f < N_ * K_; f += 256) {
        const int j = f >> 4, k = f & 15;
        v_t[k * 513 + j] = vb[f];
    }
    for (int f = tid; f < N_; f += 256) q_lds[f] = q[b * N_ + f];
    __syncthreads();

    const int i = i0 + wid;

    float vi[16];
    #pragma unroll
    for (int k = 0; k < 16; ++k) vi[k] = v_t[k * 513 + i];   // broadcast
    const float qi = q_lds[i];

    float w1[16], w2[16];
    #pragma unroll
    for (int k = 0; k < 16; ++k) { w1[k] = 0.f; w2[k] = 0.f; }
    float sacc = 0.f, R = 0.f;

    const size_t betaBase = (((size_t)b * H_) * N_ + i) * N_;

    for (int p = 0; p < 8; ++p) {
        const int j = lane + (p << 6);
        const float* bp = beta + betaBase + j;
        float r = 0.f;
        #pragma unroll
        for (int h = 0; h < H_; ++h) r += bp[(size_t)h * NN_];
        r *= 0.125f;   // mean over heads

        float vj[16];
        #pragma unroll
        for (int k = 0; k < 16; ++k) vj[k] = v_t[k * 513 + j];

        float d0 = 0.f, d1 = 0.f, d2 = 0.f, d3 = 0.f;
        #pragma unroll
        for (int k = 0; k < 16; k += 4) {
            d0 = fmaf(vi[k],   vj[k],   d0);
            d1 = fmaf(vi[k+1], vj[k+1], d1);
            d2 = fmaf(vi[k+2], vj[k+2], d2);
            d3 = fmaf(vi[k+3], vj[k+3], d3);
        }
        #pragma unroll
        for (int k = 0; k < 16; ++k) w1[k] = fmaf(r, vj[k], w1[k]);

        const float kl  = qi + q_lds[j] - ((d0 + d1) + (d2 + d3));
        const float rkl = r * kl;
        #pragma unroll
        for (int k = 0; k < 16; ++k) w2[k] = fmaf(rkl, vj[k], w2[k]);
        sacc += rkl;
        R    += r;
    }

    // wave-wide butterfly: every lane ends with the full sums
    #pragma unroll
    for (int off = 32; off > 0; off >>= 1) {
        #pragma unroll
        for (int k = 0; k < 16; ++k) {
            w1[k] += __shfl_xor(w1[k], off, 64);
            w2[k] += __shfl_xor(w2[k], off, 64);
        }
        sacc += __shfl_xor(sacc, off, 64);
        R    += __shfl_xor(R,    off, 64);
    }

    // gvec = (1-s)(R*vi - w1) + s*vi - w2  (in the rotated frame)
    float gvec[16];
    #pragma unroll
    for (int k = 0; k < 16; ++k)
        gvec[k] = (1.0f - sacc) * (R * vi[k] - w1[k]) + sacc * vi[k] - w2[k];

    if (lane < 16) {
        const float lr = lrp[0];
        const size_t rowi = (size_t)b * N_ + i;
        const float* omr = Om + rowi * 256 + (size_t)lane * 16;
        float S = 0.f;
        #pragma unroll
        for (int c2 = 0; c2 < 16; ++c2) S = fmaf(omr[c2], gvec[c2], S);
        const size_t oi = rowi * 16 + lane;
        const float m0 = mu[oi], mp = mu_prior[oi];
        out[oi] = m0 - lr * (ALPHA_C * (m0 - mp) + S);
    }
}

// -------------------------------------------------------------------------
extern "C" void kernel_launch(void* const* d_in, const int* in_sizes, int n_in,
                              void* d_out, int out_size, void* d_ws, size_t ws_size,
                              hipStream_t stream)
{
    const float* mu   = (const float*)d_in[0];
    const float* beta = (const float*)d_in[1];
    const float* mup  = (const float*)d_in[2];
    const float* phi  = (const float*)d_in[3];
    const float* gen  = (const float*)d_in[4];
    const float* lr   = (const float*)d_in[5];
    float* out = (float*)d_out;

    float* Om = (float*)d_ws;                       // 4096*256 floats = 4 MB
    float* v  = Om + (size_t)4096 * 256;            // 4096*16
    float* q  = v  + (size_t)4096 * 16;             // 4096

    expm_kernel<<<B_ * N_, 256, 0, stream>>>(mu, phi, gen, Om, v, q);
    grad_kernel<<<B_ * (N_ / 4), 256, 0, stream>>>(mu, beta, mup, lr, Om, v, q, out);
}